// Round 4
// baseline (406.691 us; speedup 1.0000x reference)
//
#include <hip/hip_runtime.h>
#include <stdint.h>

#define B_ 4
#define L_ 4096
#define H_ 8
#define D_ 64
#define S_ 45
#define U_ 45
#define BH_ 32
#define STRIDE_ (H_*D_)            // 512 floats between consecutive l
#define BSTR_ ((size_t)L_*H_*D_)   // 2097152 floats per batch

// index_sample declared int64 in the reference; harness may pass int32 or int64.
// Detect layout from data: int64 => odd int32 slots (high words) all zero.
__device__ __forceinline__ bool detect_idx64(const int* idxp){
    bool z = true;
    #pragma unroll
    for (int i = 1; i < 32; i += 2) z = z && (idxp[i] == 0);
    return z;
}

// ---------- kernel A: M[bh][q] = max_s(dot) - sum_s(dot)/L ----------
// 4 lanes per gathered K-row: 16 FMA + 2 shuffles per row (vs 4 FMA + 4
// shuffles in the 16-lane scheme) -> 8x fewer ds_swizzles per row.
// Blocks 0..7 also zero the mean accumulator (saves a dispatch).
__global__ __launch_bounds__(256) void kM(const float* __restrict__ Qb,
                                          const float* __restrict__ Kb,
                                          const int* __restrict__ idxp,
                                          float* __restrict__ Mout,
                                          float* __restrict__ meanZ){
    if (blockIdx.x < 8) meanZ[blockIdx.x*256 + threadIdx.x] = 0.f;

    int g = blockIdx.x;                 // 0..2047
    int xcd  = g & 7;
    int slot = g >> 3;                  // 0..255
    int bh   = xcd*4 + (slot >> 6);     // bh varies slowest within an XCD
    int chunk= slot & 63;               // 64-query chunk
    int b = bh >> 3, h = bh & 7;
    int q0 = chunk * 64;
    bool idx64 = detect_idx64(idxp);

    __shared__ float qs[64][64];        // 16 KB Q tile
    for (int i = threadIdx.x; i < 64*16; i += 256){
        int qrow = i >> 4, c = i & 15;
        float4 v = ((const float4*)(Qb + (size_t)b*BSTR_ + (size_t)(q0+qrow)*STRIDE_ + h*D_))[c];
        *(float4*)&qs[qrow][c*4] = v;
    }
    __syncthreads();

    int lane4 = threadIdx.x & 3;        // position within 4-lane row group
    int grp   = (threadIdx.x >> 2) & 15;
    int wv    = threadIdx.x >> 6;
    int qrow  = wv*16 + grp;            // 0..63
    int qg    = q0 + qrow;

    float4 qf[4];
    #pragma unroll
    for (int j = 0; j < 4; j++) qf[j] = *(const float4*)&qs[qrow][lane4*4 + j*16];

    const float* kbase = Kb + (size_t)b*BSTR_ + h*D_;
    float mx = -1e30f, sm = 0.f;
    #pragma unroll 3
    for (int s = 0; s < S_; s++){
        int flat = qg * S_ + s;
        int ki = idx64 ? idxp[2*flat] : idxp[flat];
        const float* kr = kbase + (size_t)ki*STRIDE_;
        float a0 = 0.f, a1 = 0.f, a2 = 0.f, a3 = 0.f;
        float4 k0 = *(const float4*)(kr + lane4*4);
        float4 k1 = *(const float4*)(kr + lane4*4 + 16);
        float4 k2 = *(const float4*)(kr + lane4*4 + 32);
        float4 k3 = *(const float4*)(kr + lane4*4 + 48);
        a0 = fmaf(qf[0].x,k0.x,a0); a0 = fmaf(qf[0].y,k0.y,a0);
        a0 = fmaf(qf[0].z,k0.z,a0); a0 = fmaf(qf[0].w,k0.w,a0);
        a1 = fmaf(qf[1].x,k1.x,a1); a1 = fmaf(qf[1].y,k1.y,a1);
        a1 = fmaf(qf[1].z,k1.z,a1); a1 = fmaf(qf[1].w,k1.w,a1);
        a2 = fmaf(qf[2].x,k2.x,a2); a2 = fmaf(qf[2].y,k2.y,a2);
        a2 = fmaf(qf[2].z,k2.z,a2); a2 = fmaf(qf[2].w,k2.w,a2);
        a3 = fmaf(qf[3].x,k3.x,a3); a3 = fmaf(qf[3].y,k3.y,a3);
        a3 = fmaf(qf[3].z,k3.z,a3); a3 = fmaf(qf[3].w,k3.w,a3);
        float p = (a0+a1) + (a2+a3);
        p += __shfl_xor(p, 1);
        p += __shfl_xor(p, 2);
        mx = fmaxf(mx, p); sm += p;
    }
    if (lane4 == 0) Mout[bh * L_ + qg] = mx - sm * (1.0f / L_);
}

// ---------- kernel B1: wave-local top-45 per 512-element segment ----------
// One wave per (seg,bh). No barriers: 45 iterations of shfl-butterfly argmax.
__global__ __launch_bounds__(64) void kTop1(const float* __restrict__ M,
                                            float* __restrict__ candV,
                                            int*   __restrict__ candI){
    int seg = blockIdx.x, bh = blockIdx.y;
    int lane = threadIdx.x;
    const float* Mr = M + (size_t)bh*L_ + seg*512;
    float v[8];
    #pragma unroll
    for (int j = 0; j < 8; j++) v[j] = Mr[lane + 64*j];

    for (int it = 0; it < U_; it++){
        float best = -1e30f; int bidx = 0x7fffffff;
        #pragma unroll
        for (int j = 0; j < 8; j++){
            int id = lane + 64*j;
            if (v[j] > best || (v[j] == best && id < bidx)){ best = v[j]; bidx = id; }
        }
        #pragma unroll
        for (int off = 1; off < 64; off <<= 1){
            float ov = __shfl_xor(best, off); int oi = __shfl_xor(bidx, off);
            if (ov > best || (ov == best && oi < bidx)){ best = ov; bidx = oi; }
        }
        if (lane == 0){
            candV[((size_t)bh*8 + seg)*U_ + it] = best;
            candI[((size_t)bh*8 + seg)*U_ + it] = seg*512 + bidx;
        }
        if (lane == (bidx & 63)) v[bidx >> 6] = -1e30f;
    }
}

// ---------- kernel B2: merge 8x45 candidates -> global top-45 per bh ----------
__global__ __launch_bounds__(64) void kTop2(const float* __restrict__ candV,
                                            const int*   __restrict__ candI,
                                            int* __restrict__ Mtop){
    int bh = blockIdx.x;
    int lane = threadIdx.x;
    float v[6]; int idv[6];
    #pragma unroll
    for (int j = 0; j < 6; j++){
        int slot = lane + 64*j;
        if (slot < 8*U_){
            v[j]   = candV[(size_t)bh*8*U_ + slot];
            idv[j] = candI[(size_t)bh*8*U_ + slot];
        } else { v[j] = -1e30f; idv[j] = 0x7fffffff; }
    }
    for (int it = 0; it < U_; it++){
        float best = -1e30f; int bidx = 0x7fffffff; int bj = 0;
        #pragma unroll
        for (int j = 0; j < 6; j++){
            if (v[j] > best || (v[j] == best && idv[j] < bidx)){ best = v[j]; bidx = idv[j]; bj = j; }
        }
        float myBest = best; int myIdx = bidx;
        #pragma unroll
        for (int off = 1; off < 64; off <<= 1){
            float ov = __shfl_xor(best, off); int oi = __shfl_xor(bidx, off);
            if (ov > best || (ov == best && oi < bidx)){ best = ov; bidx = oi; }
        }
        if (lane == 0) Mtop[bh*U_ + it] = bidx;
        if (myBest == best && myIdx == bidx) v[bj] = -1e30f;   // unique owner (idx unique)
    }
}

// ---------- kernel C: V column sums -> atomicAdd into mean (holds SUM) ----------
__global__ __launch_bounds__(256) void kVsum(const float* __restrict__ Vb,
                                             float* __restrict__ mean){
    int bh = blockIdx.y, b = bh >> 3, h = bh & 7; int chunk = blockIdx.x; // 16
    int d8 = threadIdx.x & 7, sub = threadIdx.x >> 3;                    // 32 subs
    float acc[8];
    #pragma unroll
    for (int j = 0; j < 8; j++) acc[j] = 0.f;
    for (int i = 0; i < 8; i++){
        int l = chunk*256 + sub + 32*i;
        const float4* V4 = (const float4*)(Vb + (size_t)b*BSTR_ + (size_t)l*STRIDE_ + h*D_);
        float4 a = V4[d8*2], c4 = V4[d8*2+1];
        acc[0] += a.x;  acc[1] += a.y;  acc[2] += a.z;  acc[3] += a.w;
        acc[4] += c4.x; acc[5] += c4.y; acc[6] += c4.z; acc[7] += c4.w;
    }
    __shared__ float red[32][64];
    #pragma unroll
    for (int j = 0; j < 8; j++) red[sub][d8*8+j] = acc[j];
    __syncthreads();
    if (threadIdx.x < 64){
        float s = 0.f;
        for (int k = 0; k < 32; k++) s += red[k][threadIdx.x];
        atomicAdd(&mean[bh*64 + threadIdx.x], s);
    }
}

// ---------- fused flash split-k: scores + online softmax + PV partials ----------
// Grid (kc=16, bh=32), 256 threads, ~58 KB LDS -> exactly 2 blocks/CU.
__global__ __launch_bounds__(256) void kAttnPart(const float* __restrict__ Qb,
                                                 const float* __restrict__ Kb,
                                                 const float* __restrict__ Vb,
                                                 const int*   __restrict__ Mtop,
                                                 float* __restrict__ Opart,
                                                 float* __restrict__ mlG){
    int bh = blockIdx.y, b = bh >> 3, h = bh & 7; int kc = blockIdx.x;
    int t = threadIdx.x;
    __shared__ float S[48][260];          // 49.9 KB scores (pad: b128-aligned rows)
    __shared__ float red[4][8][64];       // 8 KB
    __shared__ int   qidx[U_];

    if (t < U_) qidx[t] = Mtop[bh*U_ + t];
    __syncthreads();

    // Phase 1: scores for this block's 256 keys, all 45 queries.
    int k = kc*256 + t;
    float4 kf[16];
    const float4* K4 = (const float4*)(Kb + (size_t)b*BSTR_ + (size_t)k*STRIDE_ + h*D_);
    #pragma unroll
    for (int c = 0; c < 16; c++) kf[c] = K4[c];
    #pragma unroll 3
    for (int u = 0; u < U_; u++){
        int qi = __builtin_amdgcn_readfirstlane(qidx[u]);   // wave-uniform -> s_load path
        const float4* qp = (const float4*)(Qb + (size_t)b*BSTR_ + (size_t)qi*STRIDE_ + h*D_);
        float a0=0.f, a1=0.f, a2=0.f, a3=0.f;
        #pragma unroll
        for (int c = 0; c < 16; c++){
            float4 qv = qp[c];
            a0 = fmaf(qv.x, kf[c].x, a0);
            a1 = fmaf(qv.y, kf[c].y, a1);
            a2 = fmaf(qv.z, kf[c].z, a2);
            a3 = fmaf(qv.w, kf[c].w, a3);
        }
        S[u][t] = ((a0+a1)+(a2+a3)) * 0.125f;
    }
    __syncthreads();

    // Phase 2: per-u softmax partial over this chunk's 256 scores (one wave per u).
    int wv = t >> 6, lane = t & 63;
    for (int u = wv; u < U_; u += 4){
        float4 sv = *(const float4*)&S[u][lane*4];
        float m = fmaxf(fmaxf(sv.x, sv.y), fmaxf(sv.z, sv.w));
        #pragma unroll
        for (int off = 1; off < 64; off <<= 1) m = fmaxf(m, __shfl_xor(m, off));
        float e0 = __expf(sv.x - m), e1 = __expf(sv.y - m);
        float e2 = __expf(sv.z - m), e3 = __expf(sv.w - m);
        float ls = (e0+e1)+(e2+e3);
        #pragma unroll
        for (int off = 1; off < 64; off <<= 1) ls += __shfl_xor(ls, off);
        float4 pv; pv.x = e0; pv.y = e1; pv.z = e2; pv.w = e3;
        *(float4*)&S[u][lane*4] = pv;
        if (lane == 0){
            size_t mi = ((size_t)(bh*16 + kc)*U_ + u)*2;
            mlG[mi] = m; mlG[mi+1] = ls;
        }
    }
    __syncthreads();

    // Phase 3: Opart[u][d] = sum_k P[u][k] * V[k][d] over this 256-key chunk.
    int d8 = t & 7, ks = t >> 3;          // ks 0..31
    for (int g = 0; g < 6; g++){
        int u0 = g*8; int nu = (U_ - u0 < 8) ? (U_ - u0) : 8;
        float acc[8][8];
        #pragma unroll
        for (int r = 0; r < 8; r++)
            #pragma unroll
            for (int j = 0; j < 8; j++) acc[r][j] = 0.f;
        for (int i = 0; i < 8; i++){
            int kk = ks + 32*i;
            const float4* V4 = (const float4*)(Vb + (size_t)b*BSTR_ +
                        (size_t)(kc*256 + kk)*STRIDE_ + h*D_);
            float4 va = V4[d8*2], vb = V4[d8*2+1];
            float vf[8] = {va.x, va.y, va.z, va.w, vb.x, vb.y, vb.z, vb.w};
            #pragma unroll
            for (int r = 0; r < 8; r++){
                float p = S[u0+r][kk];    // rows >= nu: garbage, discarded below
                #pragma unroll
                for (int j = 0; j < 8; j++) acc[r][j] = fmaf(p, vf[j], acc[r][j]);
            }
        }
        #pragma unroll
        for (int off = 8; off <= 32; off <<= 1)
            #pragma unroll
            for (int r = 0; r < 8; r++)
                #pragma unroll
                for (int j = 0; j < 8; j++) acc[r][j] += __shfl_xor(acc[r][j], off);
        if (lane < 8){
            for (int r = 0; r < 8; r++)
                #pragma unroll
                for (int j = 0; j < 8; j++) red[wv][r][d8*8+j] = acc[r][j];
        }
        __syncthreads();
        for (int tt = t; tt < nu*64; tt += 256){
            int r = tt >> 6, d = tt & 63;
            float s = red[0][r][d] + red[1][r][d] + red[2][r][d] + red[3][r][d];
            Opart[((size_t)(bh*16 + kc)*U_ + u0 + r)*64 + d] = s;
        }
        __syncthreads();
    }
}

// ---------- kernel E: fill output with V-mean (mean holds SUM; scale here) ----------
__global__ __launch_bounds__(256) void kFill(const float* __restrict__ mean,
                                             float* __restrict__ out){
    size_t t = (size_t)blockIdx.x*256 + threadIdx.x;   // one float4 each; 2,097,152 total
    int d16 = (int)(t & 15); int h = (int)((t >> 4) & 7); int b = (int)(t >> 19);
    int bh = b*8 + h;
    float4 o = *(const float4*)(mean + bh*64 + d16*4);
    const float inv = 1.0f / L_;
    o.x *= inv; o.y *= inv; o.z *= inv; o.w *= inv;
    ((float4*)out)[t] = o;
}

// ---------- merge 16 split-k partials and scatter the 45 rows per bh ----------
__global__ __launch_bounds__(256) void kAttnMerge(const float* __restrict__ Opart,
                                                  const float* __restrict__ mlG,
                                                  const int*   __restrict__ Mtop,
                                                  float* __restrict__ out){
    int bh = blockIdx.x, b = bh >> 3, h = bh & 7;
    int t = threadIdx.x;
    int usub = t >> 6, d = t & 63;
    for (int p = 0; p < 12; p++){
        int u = p*4 + usub;
        if (u >= U_) continue;
        float mstar = -1e30f;
        for (int kc = 0; kc < 16; kc++)
            mstar = fmaxf(mstar, mlG[((size_t)(bh*16 + kc)*U_ + u)*2]);
        float lsum = 0.f, acc = 0.f;
        for (int kc = 0; kc < 16; kc++){
            size_t mi = ((size_t)(bh*16 + kc)*U_ + u)*2;
            float w = __expf(mlG[mi] - mstar);
            lsum = fmaf(mlG[mi+1], w, lsum);
            acc  = fmaf(w, Opart[((size_t)(bh*16 + kc)*U_ + u)*64 + d], acc);
        }
        int qi = Mtop[bh*U_ + u];
        out[(size_t)b*BSTR_ + (size_t)qi*STRIDE_ + h*D_ + d] = acc / lsum;
    }
}

extern "C" void kernel_launch(void* const* d_in, const int* in_sizes, int n_in,
                              void* d_out, int out_size, void* d_ws, size_t ws_size,
                              hipStream_t stream) {
    const float* Qb  = (const float*)d_in[0];
    const float* Kb  = (const float*)d_in[1];
    const float* Vb  = (const float*)d_in[2];
    const int*   idx = (const int*)d_in[3];
    float* out = (float*)d_out;

    float* ws = (float*)d_ws;
    // ws layout (float offsets)
    float* M      = ws;                      // 131072
    float* candV  = ws + 131072;             // 32*8*45 = 11520 (pad 12288)
    int*   candI  = (int*)(ws + 143360);     // 11520 (pad 12288)
    int*   Mtop   = (int*)(ws + 155648);     // 1440 (pad 2048)
    float* mean   = ws + 157696;             // 2048 (SUM; zeroed in kM, scaled in kFill)
    float* mlG    = ws + 159744;             // 32*16*45*2 = 46080 (pad 49152)
    float* Opart  = ws + 208896;             // 32*16*45*64 = 1474560
    // total = 1,683,456 floats = 6.7 MB

    dim3 blk256(256);
    kM        <<<dim3(2048),   blk256, 0, stream>>>(Qb, Kb, idx, M, mean);
    kTop1     <<<dim3(8, 32),  dim3(64), 0, stream>>>(M, candV, candI);
    kTop2     <<<dim3(32),     dim3(64), 0, stream>>>(candV, candI, Mtop);
    kVsum     <<<dim3(16, 32), blk256, 0, stream>>>(Vb, mean);
    kAttnPart <<<dim3(16, 32), blk256, 0, stream>>>(Qb, Kb, Vb, Mtop, Opart, mlG);
    kFill     <<<dim3(8192),   blk256, 0, stream>>>(mean, out);
    kAttnMerge<<<dim3(32),     blk256, 0, stream>>>(Opart, mlG, Mtop, out);
}

// Round 5
// 349.472 us; speedup vs baseline: 1.1637x; 1.1637x over previous
//
#include <hip/hip_runtime.h>
#include <stdint.h>

#define B_ 4
#define L_ 4096
#define H_ 8
#define D_ 64
#define S_ 45
#define U_ 45
#define BH_ 32
#define STRIDE_ (H_*D_)            // 512 floats between consecutive l
#define BSTR_ ((size_t)L_*H_*D_)   // 2097152 floats per batch

// index_sample declared int64 in the reference; harness may pass int32 or int64.
// Detect layout from data: int64 => odd int32 slots (high words) all zero.
__device__ __forceinline__ bool detect_idx64(const int* idxp){
    bool z = true;
    #pragma unroll
    for (int i = 1; i < 32; i += 2) z = z && (idxp[i] == 0);
    return z;
}

// ---------- kernel A: M[bh][q] = max_s(dot) - sum_s(dot)/L ----------
// 8 lanes per gathered K-row: each lane loads 2 float4s so each of the two
// load instructions covers exactly one 128B cache line per row (2 L2 line
// requests/row = the gather floor). 3 shuffles per 8 rows. Full occupancy.
__global__ __launch_bounds__(256) void kM(const float* __restrict__ Qb,
                                          const float* __restrict__ Kb,
                                          const int* __restrict__ idxp,
                                          float* __restrict__ Mout){
    int g = blockIdx.x;                 // 0..2047
    int xcd  = g & 7;
    int slot = g >> 3;                  // 0..255
    int bh   = xcd*4 + (slot >> 6);     // bh varies slowest within an XCD
    int chunk= slot & 63;               // 64-query chunk
    int b = bh >> 3, h = bh & 7;
    int q0 = chunk * 64;
    bool idx64 = detect_idx64(idxp);

    __shared__ float qs[64][64];        // 16 KB Q tile
    for (int i = threadIdx.x; i < 64*16; i += 256){
        int qrow = i >> 4, c = i & 15;
        float4 v = ((const float4*)(Qb + (size_t)b*BSTR_ + (size_t)(q0+qrow)*STRIDE_ + h*D_))[c];
        *(float4*)&qs[qrow][c*4] = v;
    }
    __syncthreads();

    int lane8 = threadIdx.x & 7;        // position within 8-lane row group
    const float* kbase = Kb + (size_t)b*BSTR_ + h*D_;

    for (int qq = 0; qq < 2; qq++){
        int qrow = (threadIdx.x >> 3) + 32*qq;   // 0..63
        int qg   = q0 + qrow;
        float4 qf0 = *(const float4*)&qs[qrow][lane8*4];
        float4 qf1 = *(const float4*)&qs[qrow][lane8*4 + 32];
        float mx = -1e30f, sm = 0.f;
        #pragma unroll 3
        for (int s = 0; s < S_; s++){
            int flat = qg * S_ + s;
            int ki = idx64 ? idxp[2*flat] : idxp[flat];
            const float* kr = kbase + (size_t)ki*STRIDE_;
            float4 k0 = *(const float4*)(kr + lane8*4);        // line 0 of row
            float4 k1 = *(const float4*)(kr + lane8*4 + 32);   // line 1 of row
            float a0 = qf0.x*k0.x;
            a0 = fmaf(qf0.y, k0.y, a0);
            a0 = fmaf(qf0.z, k0.z, a0);
            a0 = fmaf(qf0.w, k0.w, a0);
            float a1 = qf1.x*k1.x;
            a1 = fmaf(qf1.y, k1.y, a1);
            a1 = fmaf(qf1.z, k1.z, a1);
            a1 = fmaf(qf1.w, k1.w, a1);
            float p = a0 + a1;
            p += __shfl_xor(p, 1);
            p += __shfl_xor(p, 2);
            p += __shfl_xor(p, 4);
            mx = fmaxf(mx, p); sm += p;
        }
        if (lane8 == 0) Mout[bh * L_ + qg] = mx - sm * (1.0f / L_);
    }
}

// ---------- fused top-45 per (b,h): 8 segment waves + wave-0 merge ----------
// Also zeroes the mean accumulator (consumed by kAttnPart's atomics).
__global__ __launch_bounds__(512) void kTopF(const float* __restrict__ M,
                                             int* __restrict__ Mtop,
                                             float* __restrict__ meanZ){
    int bh = blockIdx.x;
    int t = threadIdx.x;
    if (t < 64) meanZ[bh*64 + t] = 0.f;
    __shared__ float cV[8*U_];
    __shared__ int   cI[8*U_];
    int wv = t >> 6, lane = t & 63;      // wv = segment 0..7
    const float* Mr = M + (size_t)bh*L_ + wv*512;
    float v[8];
    #pragma unroll
    for (int j = 0; j < 8; j++) v[j] = Mr[lane + 64*j];

    for (int it = 0; it < U_; it++){
        float best = -1e30f; int bidx = 0x7fffffff;
        #pragma unroll
        for (int j = 0; j < 8; j++){
            int id = lane + 64*j;
            if (v[j] > best){ best = v[j]; bidx = id; }   // ascending id scan
        }
        #pragma unroll
        for (int off = 1; off < 64; off <<= 1){
            float ov = __shfl_xor(best, off); int oi = __shfl_xor(bidx, off);
            if (ov > best || (ov == best && oi < bidx)){ best = ov; bidx = oi; }
        }
        if (lane == 0){ cV[wv*U_ + it] = best; cI[wv*U_ + it] = wv*512 + bidx; }
        if (lane == (bidx & 63)) v[bidx >> 6] = -1e30f;
    }
    __syncthreads();
    if (t < 64){
        float v2[6]; int id2[6];
        #pragma unroll
        for (int j = 0; j < 6; j++){
            int slot = t + 64*j;
            if (slot < 8*U_){ v2[j] = cV[slot]; id2[j] = cI[slot]; }
            else            { v2[j] = -1e30f;  id2[j] = 0x7fffffff; }
        }
        for (int it = 0; it < U_; it++){
            float best = -1e30f; int bidx = 0x7fffffff; int bj = 0;
            #pragma unroll
            for (int j = 0; j < 6; j++){
                if (v2[j] > best || (v2[j] == best && id2[j] < bidx)){
                    best = v2[j]; bidx = id2[j]; bj = j;
                }
            }
            float myBest = best; int myIdx = bidx;
            #pragma unroll
            for (int off = 1; off < 64; off <<= 1){
                float ov = __shfl_xor(best, off); int oi = __shfl_xor(bidx, off);
                if (ov > best || (ov == best && oi < bidx)){ best = ov; bidx = oi; }
            }
            if (t == 0) Mtop[bh*U_ + it] = bidx;
            if (myBest == best && myIdx == bidx) v2[bj] = -1e30f;  // unique owner
        }
    }
}

// ---------- fused flash split-k: scores + softmax partials + PV + V-sum ----------
// Grid (kc=16, bh=32), 256 threads, ~58 KB LDS -> 2 blocks/CU (grid = exactly 2/CU).
__global__ __launch_bounds__(256) void kAttnPart(const float* __restrict__ Qb,
                                                 const float* __restrict__ Kb,
                                                 const float* __restrict__ Vb,
                                                 const int*   __restrict__ Mtop,
                                                 float* __restrict__ Opart,
                                                 float* __restrict__ mlG,
                                                 float* __restrict__ mean){
    int bh = blockIdx.y, b = bh >> 3, h = bh & 7; int kc = blockIdx.x;
    int t = threadIdx.x;
    __shared__ float S[48][260];          // 49.9 KB scores (16B-aligned rows)
    __shared__ float red[4][8][64];       // 8 KB
    __shared__ int   qidx[U_];

    if (t < U_) qidx[t] = Mtop[bh*U_ + t];
    __syncthreads();

    // Phase 1: scores for this block's 256 keys, all 45 queries.
    int k = kc*256 + t;
    float4 kf[16];
    const float4* K4 = (const float4*)(Kb + (size_t)b*BSTR_ + (size_t)k*STRIDE_ + h*D_);
    #pragma unroll
    for (int c = 0; c < 16; c++) kf[c] = K4[c];
    #pragma unroll 3
    for (int u = 0; u < U_; u++){
        int qi = __builtin_amdgcn_readfirstlane(qidx[u]);   // wave-uniform -> scalar loads
        const float4* qp = (const float4*)(Qb + (size_t)b*BSTR_ + (size_t)qi*STRIDE_ + h*D_);
        float a0=0.f, a1=0.f, a2=0.f, a3=0.f;
        #pragma unroll
        for (int c = 0; c < 16; c++){
            float4 qv = qp[c];
            a0 = fmaf(qv.x, kf[c].x, a0);
            a1 = fmaf(qv.y, kf[c].y, a1);
            a2 = fmaf(qv.z, kf[c].z, a2);
            a3 = fmaf(qv.w, kf[c].w, a3);
        }
        S[u][t] = ((a0+a1)+(a2+a3)) * 0.125f;
    }
    __syncthreads();

    // Phase 2: per-u softmax partial over this chunk's 256 scores (one wave per u).
    int wv = t >> 6, lane = t & 63;
    for (int u = wv; u < U_; u += 4){
        float4 sv = *(const float4*)&S[u][lane*4];
        float m = fmaxf(fmaxf(sv.x, sv.y), fmaxf(sv.z, sv.w));
        #pragma unroll
        for (int off = 1; off < 64; off <<= 1) m = fmaxf(m, __shfl_xor(m, off));
        float e0 = __expf(sv.x - m), e1 = __expf(sv.y - m);
        float e2 = __expf(sv.z - m), e3 = __expf(sv.w - m);
        float ls = (e0+e1)+(e2+e3);
        #pragma unroll
        for (int off = 1; off < 64; off <<= 1) ls += __shfl_xor(ls, off);
        float4 pv; pv.x = e0; pv.y = e1; pv.z = e2; pv.w = e3;
        *(float4*)&S[u][lane*4] = pv;
        if (lane == 0){
            size_t mi = ((size_t)(bh*16 + kc)*U_ + u)*2;
            mlG[mi] = m; mlG[mi+1] = ls;
        }
    }
    __syncthreads();

    // Phase 3: Opart[u][d] = sum_k P[u][k] * V[k][d]; V column-sum folded into g==0.
    int d8 = t & 7, ks = t >> 3;          // ks 0..31
    float vsum[8];
    #pragma unroll
    for (int j = 0; j < 8; j++) vsum[j] = 0.f;
    for (int g = 0; g < 6; g++){
        int u0 = g*8; int nu = (U_ - u0 < 8) ? (U_ - u0) : 8;
        float acc[8][8];
        #pragma unroll
        for (int r = 0; r < 8; r++)
            #pragma unroll
            for (int j = 0; j < 8; j++) acc[r][j] = 0.f;
        for (int i = 0; i < 8; i++){
            int kk = ks + 32*i;
            const float4* V4 = (const float4*)(Vb + (size_t)b*BSTR_ +
                        (size_t)(kc*256 + kk)*STRIDE_ + h*D_);
            float4 va = V4[d8*2], vb = V4[d8*2+1];
            float vf[8] = {va.x, va.y, va.z, va.w, vb.x, vb.y, vb.z, vb.w};
            if (g == 0){
                #pragma unroll
                for (int j = 0; j < 8; j++) vsum[j] += vf[j];
            }
            #pragma unroll
            for (int r = 0; r < 8; r++){
                float p = S[u0+r][kk];    // rows >= nu: garbage, discarded below
                #pragma unroll
                for (int j = 0; j < 8; j++) acc[r][j] = fmaf(p, vf[j], acc[r][j]);
            }
        }
        #pragma unroll
        for (int off = 8; off <= 32; off <<= 1)
            #pragma unroll
            for (int r = 0; r < 8; r++)
                #pragma unroll
                for (int j = 0; j < 8; j++) acc[r][j] += __shfl_xor(acc[r][j], off);
        if (lane < 8){
            for (int r = 0; r < 8; r++)
                #pragma unroll
                for (int j = 0; j < 8; j++) red[wv][r][d8*8+j] = acc[r][j];
        }
        __syncthreads();
        for (int tt = t; tt < nu*64; tt += 256){
            int r = tt >> 6, d = tt & 63;
            float s = red[0][r][d] + red[1][r][d] + red[2][r][d] + red[3][r][d];
            Opart[((size_t)(bh*16 + kc)*U_ + u0 + r)*64 + d] = s;
        }
        __syncthreads();
    }
    // V column-sum: reduce vsum over ks within wave, then across waves, atomicAdd.
    #pragma unroll
    for (int off = 8; off <= 32; off <<= 1)
        #pragma unroll
        for (int j = 0; j < 8; j++) vsum[j] += __shfl_xor(vsum[j], off);
    if (lane < 8){
        #pragma unroll
        for (int j = 0; j < 8; j++) red[wv][0][lane*8 + j] = vsum[j];
    }
    __syncthreads();
    if (t < 64){
        float s = red[0][0][t] + red[1][0][t] + red[2][0][t] + red[3][0][t];
        atomicAdd(&mean[bh*64 + t], s);
    }
}

// ---------- kernel E: fill output with V-mean (mean holds SUM; scale here) ----------
__global__ __launch_bounds__(256) void kFill(const float* __restrict__ mean,
                                             float* __restrict__ out){
    size_t t = (size_t)blockIdx.x*256 + threadIdx.x;   // one float4 each; 2,097,152 total
    int d16 = (int)(t & 15); int h = (int)((t >> 4) & 7); int b = (int)(t >> 19);
    int bh = b*8 + h;
    float4 o = *(const float4*)(mean + bh*64 + d16*4);
    const float inv = 1.0f / L_;
    o.x *= inv; o.y *= inv; o.z *= inv; o.w *= inv;
    ((float4*)out)[t] = o;
}

// ---------- merge 16 split-k partials, scatter: one wave per (u,bh) ----------
__global__ __launch_bounds__(64) void kMerge(const float* __restrict__ Opart,
                                             const float* __restrict__ mlG,
                                             const int*   __restrict__ Mtop,
                                             float* __restrict__ out){
    int u = blockIdx.x, bh = blockIdx.y; int b = bh >> 3, h = bh & 7;
    int d = threadIdx.x;   // 64
    float mstar = -1e30f;
    #pragma unroll
    for (int kc = 0; kc < 16; kc++)
        mstar = fmaxf(mstar, mlG[((size_t)(bh*16 + kc)*U_ + u)*2]);
    float lsum = 0.f, acc = 0.f;
    #pragma unroll
    for (int kc = 0; kc < 16; kc++){
        size_t mi = ((size_t)(bh*16 + kc)*U_ + u)*2;
        float w = __expf(mlG[mi] - mstar);
        lsum = fmaf(mlG[mi+1], w, lsum);
        acc  = fmaf(w, Opart[((size_t)(bh*16 + kc)*U_ + u)*64 + d], acc);
    }
    int qi = Mtop[bh*U_ + u];
    out[(size_t)b*BSTR_ + (size_t)qi*STRIDE_ + h*D_ + d] = acc / lsum;
}

extern "C" void kernel_launch(void* const* d_in, const int* in_sizes, int n_in,
                              void* d_out, int out_size, void* d_ws, size_t ws_size,
                              hipStream_t stream) {
    const float* Qb  = (const float*)d_in[0];
    const float* Kb  = (const float*)d_in[1];
    const float* Vb  = (const float*)d_in[2];
    const int*   idx = (const int*)d_in[3];
    float* out = (float*)d_out;

    float* ws = (float*)d_ws;
    // ws layout (float offsets)
    float* M      = ws;                      // 131072
    int*   Mtop   = (int*)(ws + 131072);     // 1440 (pad 2048)
    float* mean   = ws + 133120;             // 2048 (SUM; zeroed in kTopF, scaled in kFill)
    float* mlG    = ws + 135168;             // 32*16*45*2 = 46080 (pad 49152)
    float* Opart  = ws + 184320;             // 32*16*45*64 = 1474560
    // total = 1,658,880 floats = 6.6 MB

    kM        <<<dim3(2048),   dim3(256), 0, stream>>>(Qb, Kb, idx, M);
    kTopF     <<<dim3(32),     dim3(512), 0, stream>>>(M, Mtop, mean);
    kAttnPart <<<dim3(16, 32), dim3(256), 0, stream>>>(Qb, Kb, Vb, Mtop, Opart, mlG, mean);
    kFill     <<<dim3(8192),   dim3(256), 0, stream>>>(mean, out);
    kMerge    <<<dim3(45, 32), dim3(64),  0, stream>>>(Opart, mlG, Mtop, out);
}